// Round 9
// baseline (10151.778 us; speedup 1.0000x reference)
//
#include <hip/hip_runtime.h>
#include <cstdint>
#include <cstddef>

#define TT 512
#define NWG 256
#define SCH0 32
#define NCH0 16
#define SCH1 16
#define NCH1 32

// ---- Workspace layout (BYTE offsets).
#define OFF_H0   0ul
#define SZ_H0    (512ul*1024ul*64ul*2ul)          /* layer0 out, bf16 (T,1024,B) 64MiB */
#define OFF_OUT  (OFF_H0 + SZ_H0)
#define SZ_OUT   (512ul*512ul*64ul*4ul)           /* l1 fwd+bwd sum fp32; ALSO l0 xw dbuf */
#define OFF_XW1  (OFF_OUT + SZ_OUT)
#define SZ_XW1   (2ul*32ul*2048ul*64ul*4ul)       /* layer1 xw double buffer, 32MiB */
#define OFF_HBUF (OFF_XW1 + SZ_XW1)
#define SZ_HBUF  (2ul*2ul*2ul*512ul*64ul*4ul)     /* [layer][pp][dir] packed-h u32 */
#define OFF_CST  (OFF_HBUF + SZ_HBUF)
#define SZ_CST   (2ul*2ul*512ul*64ul*4ul)         /* unused (layout stability) */
#define OFF_FLG  (OFF_CST + SZ_CST)
#define SZ_FLG   (2ul*2ul*512ul*128ul*4ul)        /* u32 flags [layer][dir][step][slot] */
#define OFF_XWF  (OFF_FLG + SZ_FLG)
#define SZ_XWF   (2ul*2ul*512ul*4ul)              /* u32 counters [layer][dir][step] 0->16 */
#define OFF_SYN  (OFF_XWF + SZ_XWF)
#define SZ_SYN   (256ul)                          /* [0]=l0done, [1]=zcnt */
#define OFF_E    (OFF_SYN + SZ_SYN)
#define SZ_E     (64ul*512ul*4ul)
#define OFF_AT   (OFF_E + SZ_E)
#define SZ_AT    (512ul*64ul*4ul)
#define OFF_POOL (OFF_AT + SZ_AT)
#define SZ_POOL  (512ul*64ul*4ul)

#define SZB0 (2ul*(size_t)SCH0*2048ul*64ul*4ul)   /* 33.5MB l0 xw chunk; 2 fit in SZ_OUT */
#define SZB1 (2ul*(size_t)SCH1*2048ul*64ul*4ul)   /* 16.8MB l1 xw chunk; 2 fit in SZ_XW1 */

#define FUSED_LDS 53248   /* recur 32KB; gemm f32 52.2KB; gemm mfma 40KB; 2 blocks/CU */

typedef unsigned long long u64;
typedef __attribute__((ext_vector_type(8))) short short8v;   // bf16x8 MFMA frag
typedef __attribute__((ext_vector_type(4))) float f32x4;     // MFMA C/D frag

// Coherence recipe (round-8/9 lessons):
//  * cross-WG LOADS of double-buffered regions (xw) -> agent atomics (bypass
//    stale-clean L2 lines; plain loads could hit chunk c-2 data).
//  * cross-WG STORES -> PLAIN stores (full L2 bandwidth), then a RELEASE fence
//    (buffer_wbl2, writeback-only, no invalidate -> safe with concurrent
//    dirty lines) before the flag bump that publishes them.
//  * h0: plain stores by l0 recurrence + layer-end release fence + syn gate;
//    plain loads by l1 GEMM are safe (addresses never read before written this
//    launch -> no stale-clean hazard) and restore 16x L2 reuse.
//  * hbuf/flags: agent atomics (proven since round 2).
#define AHL(p)    __hip_atomic_load((p), __ATOMIC_RELAXED, __HIP_MEMORY_SCOPE_AGENT)
#define AHS(p,v)  __hip_atomic_store((p), (v), __ATOMIC_RELAXED, __HIP_MEMORY_SCOPE_AGENT)
#define AFA(p,v)  __hip_atomic_fetch_add((p), (v), __ATOMIC_RELAXED, __HIP_MEMORY_SCOPE_AGENT)
#define RELEASE_FENCE() __builtin_amdgcn_fence(__ATOMIC_RELEASE, "agent")

__device__ __forceinline__ unsigned short f2bf(float f) {   // RNE bf16
  unsigned u = __float_as_uint(f);
  u += 0x7fffu + ((u >> 16) & 1u);
  return (unsigned short)(u >> 16);
}

// ---- layer-0 xW GEMM tile (fp32 VALU path; input x fp32, K=256).
__device__ __forceinline__ void gemm_tile_f32(const float* __restrict__ X32,
                                              const float* __restrict__ W,
                                              const float* __restrict__ bias,
                                              float* __restrict__ xwout,
                                              int s0, int sch, int gtile, int sl, int d,
                                              float* Wt, float* Xt) {
  const int K = 256;
  const int tid = threadIdx.x;
  const int sg = s0 + sl;
  const int t = d ? (511 - sg) : sg;
  const int gq = tid >> 4, bq = tid & 15;
  const int g0 = gtile*128 + gq*8;

  float acc[8][4];
  #pragma unroll
  for (int i = 0; i < 8; ++i) {
    const float bv = bias[d*2048 + g0 + i];
    acc[i][0]=bv; acc[i][1]=bv; acc[i][2]=bv; acc[i][3]=bv;
  }
  const float* Wbase = W + ((size_t)d*2048 + gtile*128)*K;

  for (int kc = 0; kc < K; kc += 64) {
    __syncthreads();
    #pragma unroll
    for (int i = 0; i < 8; ++i) {
      const int f4 = i*256 + tid;
      const int row = f4 >> 4, kk4 = (f4 & 15) << 2;
      const int kk4s = kk4 ^ (((row >> 3) & 3) << 2);
      *(float4*)(Wt + row*68 + kk4s) = *(const float4*)(Wbase + (size_t)row*K + kc + kk4);
    }
    {
      const int bb = tid >> 2, kq = tid & 3;
      const float* src = X32 + ((size_t)t*64 + bb)*256 + kc + kq*16;
      #pragma unroll
      for (int i = 0; i < 4; ++i) {
        const float4 v = *(const float4*)(src + i*4);
        const int k = kq*16 + i*4;
        Xt[(k+0)*68 + bb] = v.x;
        Xt[(k+1)*68 + bb] = v.y;
        Xt[(k+2)*68 + bb] = v.z;
        Xt[(k+3)*68 + bb] = v.w;
      }
    }
    __syncthreads();
    for (int k4 = 0; k4 < 64; k4 += 4) {
      float4 w[8];
      #pragma unroll
      for (int i = 0; i < 8; ++i) {
        const int row = gq*8 + i;
        const int k4s = k4 ^ (((row >> 3) & 3) << 2);
        w[i] = *(const float4*)(Wt + row*68 + k4s);
      }
      float4 xv[4];
      #pragma unroll
      for (int kk = 0; kk < 4; ++kk) xv[kk] = *(const float4*)(Xt + (k4+kk)*68 + bq*4);
      #pragma unroll
      for (int i = 0; i < 8; ++i) {
        acc[i][0] += w[i].x*xv[0].x + w[i].y*xv[1].x + w[i].z*xv[2].x + w[i].w*xv[3].x;
        acc[i][1] += w[i].x*xv[0].y + w[i].y*xv[1].y + w[i].z*xv[2].y + w[i].w*xv[3].y;
        acc[i][2] += w[i].x*xv[0].z + w[i].y*xv[1].z + w[i].z*xv[2].z + w[i].w*xv[3].z;
        acc[i][3] += w[i].x*xv[0].w + w[i].y*xv[1].w + w[i].z*xv[2].w + w[i].w*xv[3].w;
      }
    }
  }
  // epilogue: PLAIN float4 stores (publisher fences before flag bump)
  float* op = xwout + (((size_t)d*sch + sl)*2048 + g0)*64 + bq*4;
  #pragma unroll
  for (int i = 0; i < 8; ++i)
    *(float4*)(op + (size_t)i*64) = make_float4(acc[i][0],acc[i][1],acc[i][2],acc[i][3]);
}

// ---- layer-1 xW GEMM tile (MFMA split-bf16; input h0 bf16, K=1024).
__device__ __forceinline__ void gemm_tile_mfma(const unsigned short* __restrict__ Xb,
                                               const float* __restrict__ W,
                                               const float* __restrict__ bias,
                                               float* __restrict__ xwout,
                                               int s0, int sch, int gtile, int sl, int d,
                                               unsigned short* aWb, unsigned short* aWr,
                                               unsigned short* aX) {
  const int K = 1024;
  const int tid = threadIdx.x;
  const int sg = s0 + sl;
  const int t = d ? (511 - sg) : sg;
  const int w = tid >> 6, lane = tid & 63;
  const int lhi = lane >> 4, lcol = lane & 15;
  const int g0 = gtile*128;
  const float* Wbase = W + ((size_t)d*2048 + g0)*K;
  const unsigned short* Xbase = Xb + (size_t)t*K*64;

  f32x4 acc[8];
  #pragma unroll
  for (int mt = 0; mt < 8; ++mt) acc[mt] = (f32x4){0.f,0.f,0.f,0.f};

  for (int kc = 0; kc < K; kc += 64) {
    __syncthreads();
    #pragma unroll
    for (int i = 0; i < 4; ++i) {
      const int p = i*256 + tid;
      const int row = p >> 3, o = p & 7;
      const float* src = Wbase + (size_t)row*K + kc + o*8;
      const float4 v0 = *(const float4*)(src);
      const float4 v1 = *(const float4*)(src + 4);
      const float f[8] = {v0.x,v0.y,v0.z,v0.w,v1.x,v1.y,v1.z,v1.w};
      short8v vb, vr;
      #pragma unroll
      for (int e = 0; e < 8; ++e) {
        const unsigned short hb = f2bf(f[e]);
        vb[e] = (short)hb;
        vr[e] = (short)f2bf(f[e] - __uint_as_float((unsigned)hb << 16));
      }
      const int os = o ^ (row & 7);
      *(short8v*)(aWb + (size_t)row*64 + os*8) = vb;
      *(short8v*)(aWr + (size_t)row*64 + os*8) = vr;
    }
    // stage X = h0: PLAIN loads (h0 immutable post-l0; no stale-clean hazard;
    // restores 16x L2 reuse across gtile jobs)
    #pragma unroll
    for (int i = 0; i < 4; ++i) {
      const int p = i*256 + tid;
      const int k = p >> 4, b4 = (p & 15) << 2;
      const uint2 r = *(const uint2*)(Xbase + (size_t)(kc + k)*64 + b4);
      const int o = k >> 3, e = k & 7;
      aX[((o*64 + b4+0)<<3) + e] = (unsigned short)(r.x & 0xffffu);
      aX[((o*64 + b4+1)<<3) + e] = (unsigned short)(r.x >> 16);
      aX[((o*64 + b4+2)<<3) + e] = (unsigned short)(r.y & 0xffffu);
      aX[((o*64 + b4+3)<<3) + e] = (unsigned short)(r.y >> 16);
    }
    __syncthreads();
    #pragma unroll
    for (int ks = 0; ks < 2; ++ks) {
      union { short8v v; } bx;
      bx.v = *(const short8v*)(aX + (((ks*4 + lhi)*64) + w*16 + lcol)*8);
      #pragma unroll
      for (int mt = 0; mt < 8; ++mt) {
        const int row = mt*16 + lcol;
        const int os = (ks*4 + lhi) ^ (row & 7);
        const short8v ab = *(const short8v*)(aWb + (size_t)row*64 + os*8);
        const short8v ar = *(const short8v*)(aWr + (size_t)row*64 + os*8);
        acc[mt] = __builtin_amdgcn_mfma_f32_16x16x32_bf16(ab, bx.v, acc[mt], 0, 0, 0);
        acc[mt] = __builtin_amdgcn_mfma_f32_16x16x32_bf16(ar, bx.v, acc[mt], 0, 0, 0);
      }
    }
  }
  // epilogue: PLAIN stores (publisher fences before flag bump)
  float* op = xwout + (((size_t)d*sch + sl)*2048 + g0)*64 + w*16 + lcol;
  const float* bp = bias + d*2048 + g0;
  #pragma unroll
  for (int mt = 0; mt < 8; ++mt) {
    #pragma unroll
    for (int r = 0; r < 4; ++r) {
      const int grow = mt*16 + lhi*4 + r;
      op[(size_t)grow*64] = acc[mt][r] + bp[grow];
    }
  }
}

// ---- Recurrent layer: gates = Whh16 x h via MFMA split-bf16 (round-6 body).
__device__ __forceinline__ void recur_layer(
    const float* __restrict__ Whh, char* __restrict__ wsb,
    int layer, int SCH, int NCH, float* lds)
{
  unsigned short* alds = (unsigned short*)lds;   // 32KB A-frags (value+residual)

  unsigned short* h0 = (unsigned short*)(wsb + OFF_H0);
  float* outsum  = (float*)(wsb + OFF_OUT);
  unsigned* hbase = (unsigned*)(wsb + OFF_HBUF) + (size_t)layer*131072;
  unsigned* flg  = (unsigned*)(wsb + OFF_FLG);
  unsigned* xwflg= (unsigned*)(wsb + OFF_XWF);
  unsigned* syn  = (unsigned*)(wsb + OFF_SYN);

  const int tid = threadIdx.x;
  const int d     = blockIdx.x >> 7;
  const int slot  = blockIdx.x & 127;
  const int jbase = slot << 2;

  const int w    = tid >> 6;
  const int lane = tid & 63;
  const int lhi  = lane >> 4;
  const int lcol = lane & 15;
  const int jj   = lhi;
  const int b    = w*16 + lcol;

  __builtin_amdgcn_s_setprio(1);

  for (int m = 0; m < 16; ++m) {
    const int g = m & 3, j = m >> 2;
    const float* src = Whh + ((size_t)d*2048 + g*512 + jbase + j)*512;
    for (int k = tid; k < 512; k += 256) {
      const float wv = src[k];
      const unsigned short wb = f2bf(wv);
      const unsigned short wr = f2bf(wv - __uint_as_float((unsigned)wb << 16));
      const int oct = (k >> 3) & 3;
      const int idx = (((k >> 5)*4 + oct)*16 + (m ^ oct))*8 + (k & 7);
      alds[idx] = wb;
      alds[8192 + idx] = wr;
    }
  }
  if (layer == 1 && tid == 0) {   // wait for outsum zeroing
    while (AHL(&syn[1]) < (unsigned)NWG) __builtin_amdgcn_s_sleep(2);
  }
  float creg = 0.0f;
  __syncthreads();

  const unsigned fbase = (unsigned)(layer*2 + d) * 512u;
  unsigned* xwf = xwflg + (size_t)(layer*2 + d)*512;

  for (int c = 0; c < NCH; ++c) {
    const float* xw = (const float*)(wsb + (layer ? OFF_XW1 : OFF_OUT)
                                         + (size_t)(c & 1)*(layer ? SZB1 : SZB0));
    if (tid < SCH) {   // chunk gate: whole chunk's xw produced (and fenced)
      unsigned* p = xwf + c*SCH + tid;
      while (AHL(p) < 16u) __builtin_amdgcn_s_sleep(1);
    }
    __syncthreads();

    for (int sl = 0; sl < SCH; ++sl) {
      const int sg = c*SCH + sl;
      const int t_in = d ? (511 - sg) : sg;

      // px via agent atomic loads: double-buffer reuse -> plain loads could hit
      // stale-clean L2 lines of chunk c-2. Issued pre-poll; latency hidden.
      const float* xwp = xw + ((size_t)(d*SCH + sl)*2048 + (size_t)(jbase + jj))*64 + b;
      const float px0 = AHL(xwp);
      const float px1 = AHL(xwp + 32768);
      const float px2 = AHL(xwp + 65536);
      const float px3 = AHL(xwp + 98304);

      if (sg > 0) {
        if (tid < 128) {
          unsigned* p = &flg[(size_t)(fbase + (unsigned)sg - 1u)*128 + tid];
          while (AHL(p) == 0u) __builtin_amdgcn_s_sleep(1);
        }
        __syncthreads();   // B0
      }

      const u64* hsrc = (const u64*)(hbase + ((sg & 1)*2 + d)*32768);

      u64 ring[8][4];
      #pragma unroll
      for (int ks = 0; ks < 8; ++ks) {
        const size_t hb0 = (size_t)((ks*4 + lhi)*4)*64 + b;
        ring[ks][0] = AHL(hsrc + hb0);
        ring[ks][1] = AHL(hsrc + hb0 + 64);
        ring[ks][2] = AHL(hsrc + hb0 + 128);
        ring[ks][3] = AHL(hsrc + hb0 + 192);
      }

      f32x4 acc = {0.f, 0.f, 0.f, 0.f};
      #pragma unroll
      for (int ks = 0; ks < 16; ++ks) {
        const u64 q0 = ring[ks & 7][0], q1 = ring[ks & 7][1];
        const u64 q2 = ring[ks & 7][2], q3 = ring[ks & 7][3];
        if (ks < 8) {
          const size_t hb2 = (size_t)(((ks + 8)*4 + lhi)*4)*64 + b;
          ring[ks][0] = AHL(hsrc + hb2);
          ring[ks][1] = AHL(hsrc + hb2 + 64);
          ring[ks][2] = AHL(hsrc + hb2 + 128);
          ring[ks][3] = AHL(hsrc + hb2 + 192);
        }
        union { unsigned u[4]; short8v v; } hb, rb;
        hb.u[0] = __builtin_amdgcn_perm((unsigned)(q0 >> 32), (unsigned)q0, 0x07060302u);
        rb.u[0] = __builtin_amdgcn_perm((unsigned)(q0 >> 32), (unsigned)q0, 0x05040100u);
        hb.u[1] = __builtin_amdgcn_perm((unsigned)(q1 >> 32), (unsigned)q1, 0x07060302u);
        rb.u[1] = __builtin_amdgcn_perm((unsigned)(q1 >> 32), (unsigned)q1, 0x05040100u);
        hb.u[2] = __builtin_amdgcn_perm((unsigned)(q2 >> 32), (unsigned)q2, 0x07060302u);
        rb.u[2] = __builtin_amdgcn_perm((unsigned)(q2 >> 32), (unsigned)q2, 0x05040100u);
        hb.u[3] = __builtin_amdgcn_perm((unsigned)(q3 >> 32), (unsigned)q3, 0x07060302u);
        rb.u[3] = __builtin_amdgcn_perm((unsigned)(q3 >> 32), (unsigned)q3, 0x05040100u);
        const int abase = ((ks*4 + lhi)*16 + (lcol ^ lhi))*8;
        const short8v ab = *(const short8v*)(alds + abase);
        const short8v ar = *(const short8v*)(alds + 8192 + abase);
        acc = __builtin_amdgcn_mfma_f32_16x16x32_bf16(ab, hb.v, acc, 0, 0, 0);
        acc = __builtin_amdgcn_mfma_f32_16x16x32_bf16(ab, rb.v, acc, 0, 0, 0);
        acc = __builtin_amdgcn_mfma_f32_16x16x32_bf16(ar, hb.v, acc, 0, 0, 0);
      }

      const float pi = acc[0] + px0;
      const float pf = acc[1] + px1;
      const float pg = acc[2] + px2;
      const float po = acc[3] + px3;
      const float iv = 1.0f/(1.0f + __expf(-pi));
      const float fv = 1.0f/(1.0f + __expf(-pf));
      const float gv = tanhf(pg);
      const float ov = 1.0f/(1.0f + __expf(-po));
      float cc2 = fv*creg + iv*gv;
      cc2 = fminf(fmaxf(cc2, -100.0f), 100.0f);
      creg = cc2;
      const float h = ov*tanhf(cc2);

      const unsigned short hb16 = f2bf(h);
      const unsigned short rb16 = f2bf(h - __uint_as_float((unsigned)hb16 << 16));
      const unsigned hpk = ((unsigned)hb16 << 16) | (unsigned)rb16;
      unsigned* hout = hbase + (((sg & 1) ^ 1)*2 + d)*32768;
      const int kj = jbase + jj;
      AHS(hout + ((size_t)(kj >> 1)*128 + b*2 + (kj & 1)), hpk);

      __syncthreads();   // Bend: drains each wave's vmcnt -> h stores ACKed
      if (tid == 0)
        AHS(&flg[(size_t)(fbase + (unsigned)sg)*128 + slot], 1u);
      // deferred outputs: h0 PLAIN store (published by layer-end release fence
      // + syn[0]); outsum device atomicAdd (zeros fenced before zcnt).
      if (layer == 0) {
        h0[(size_t)t_in*65536 + (size_t)(d*512 + kj)*64 + b] = hb16;
      } else {
        atomicAdd(&outsum[(size_t)t_in*32768 + (size_t)kj*64 + b], h);
      }
    }
  }
}

// ---- Mega kernel: blocks 0..255 recurrence (l0 then l1); blocks 256..511
// persistent GEMM workers, flag-paced. 512 WGs = 256 CU x 2 co-resident
// (LDS 2x52KB <= 160KB, launch_bounds(256,2)); dependency DAG acyclic.
__global__ void __launch_bounds__(256, 2) mega(
    const float* __restrict__ x,
    const float* __restrict__ Wih0, const float* __restrict__ Whh0, const float* __restrict__ b0,
    const float* __restrict__ Wih1, const float* __restrict__ Whh1, const float* __restrict__ b1,
    char* __restrict__ wsb)
{
  extern __shared__ float lds[];
  const int tid = threadIdx.x;
  unsigned* flg   = (unsigned*)(wsb + OFF_FLG);
  unsigned* xwflg = (unsigned*)(wsb + OFF_XWF);
  unsigned* syn   = (unsigned*)(wsb + OFF_SYN);

  if (blockIdx.x < NWG) {
    // -------- recurrence role --------
    recur_layer(Whh0, wsb, 0, SCH0, NCH0, lds);
    RELEASE_FENCE();   // write back dirty h0 lines (plain stores) to coherence pt
    __syncthreads();
    if (tid == 0) AFA(&syn[0], 1u);            // l0done: h0 published
    recur_layer(Whh1, wsb, 1, SCH1, NCH1, lds);
  } else {
    // -------- gemm role --------
    const int wg = blockIdx.x - NWG;
    // layer 0: f32 path, 1024 jobs/chunk -> 4 jobs/WG, all same (d, sl)
    {
      const int sl = wg >> 3, jd = (wg >> 2) & 1, gt0 = (wg & 3) * 4;
      for (int c = 0; c < NCH0; ++c) {
        if (c >= 2) {   // anti-overwrite: recurrence done with chunk c-2 (same parity)
          const unsigned gate = (unsigned)((c - 1)*SCH0 - 1);
          if (tid < 128) {
            unsigned* p = &flg[(size_t)((unsigned)(0*2 + jd)*512u + gate)*128 + tid];
            while (AHL(p) == 0u) __builtin_amdgcn_s_sleep(1);
          }
          __syncthreads();
        }
        float* xw = (float*)(wsb + OFF_OUT + (size_t)(c & 1)*SZB0);
        #pragma unroll 1
        for (int i = 0; i < 4; ++i)
          gemm_tile_f32(x, Wih0, b0, xw, c*SCH0, SCH0, gt0 + i, sl, jd, lds, lds + 128*68);
        RELEASE_FENCE();   // write back this WG's xw stores
        __syncthreads();
        if (tid == 0) AFA(&xwflg[(size_t)(0*2 + jd)*512 + c*SCH0 + sl], 4u);
      }
    }
    // wait recurrence l0 fully done (h0 written back before syn[0])
    if (tid == 0) { while (AHL(&syn[0]) < (unsigned)NWG) __builtin_amdgcn_s_sleep(2); }
    __syncthreads();
    // zero my outsum slice with plain stores, then publish
    {
      const float4 z4 = make_float4(0.f, 0.f, 0.f, 0.f);
      float4* dst = (float4*)(wsb + OFF_OUT) + (size_t)wg*16384 + tid;
      #pragma unroll
      for (int i = 0; i < 64; ++i) dst[(size_t)i*256] = z4;
    }
    RELEASE_FENCE();
    __syncthreads();
    if (tid == 0) AFA(&syn[1], 1u);            // zcnt
    // layer 1: MFMA path, 512 jobs/chunk -> 2 jobs/WG, all same (d, sl)
    {
      const unsigned short* h0p = (const unsigned short*)(wsb + OFF_H0);
      unsigned short* aWb = (unsigned short*)lds;
      unsigned short* aWr = aWb + 8192;
      unsigned short* aX  = aWr + 8192;
      const int sl = wg >> 4, jd = (wg >> 3) & 1, gt0 = (wg & 7) * 2;
      for (int c = 0; c < NCH1; ++c) {
        if (c >= 2) {
          const unsigned gate = (unsigned)((c - 1)*SCH1 - 1);
          if (tid < 128) {
            unsigned* p = &flg[(size_t)((unsigned)(2 + jd)*512u + gate)*128 + tid];
            while (AHL(p) == 0u) __builtin_amdgcn_s_sleep(1);
          }
          __syncthreads();
        }
        float* xw = (float*)(wsb + OFF_XW1 + (size_t)(c & 1)*SZB1);
        #pragma unroll 1
        for (int i = 0; i < 2; ++i)
          gemm_tile_mfma(h0p, Wih1, b1, xw, c*SCH1, SCH1, gt0 + i, sl, jd, aWb, aWr, aX);
        RELEASE_FENCE();   // write back xw stores
        __syncthreads();
        if (tid == 0) AFA(&xwflg[(size_t)(2 + jd)*512 + c*SCH1 + sl], 2u);
      }
    }
  }
}

// ---- attention / output chain (unchanged; separate dispatches -> coherent) ----
__global__ void __launch_bounds__(256) attn_logits(const float* __restrict__ outsum,
                                                   const float* __restrict__ Wa,
                                                   const float* __restrict__ ba,
                                                   float* __restrict__ e) {
  __shared__ float part[4*64];
  const int t = blockIdx.x;
  const int b = threadIdx.x & 63, jq = threadIdx.x >> 6;
  const float* base = outsum + (size_t)t * 512 * 64;
  float acc = 0.0f;
  for (int j = jq*128; j < jq*128 + 128; ++j)
    acc += base[j*64 + b] * Wa[j];
  part[jq*64 + b] = acc;
  __syncthreads();
  if (threadIdx.x < 64) {
    const int bb = threadIdx.x;
    e[bb*512 + t] = part[0*64+bb] + part[1*64+bb] + part[2*64+bb] + part[3*64+bb] + ba[0];
  }
}

__global__ void __launch_bounds__(256) attn_softmax(const float* __restrict__ e,
                                                    float* __restrict__ attn,
                                                    float* __restrict__ aT) {
  __shared__ float red[256];
  const int b = blockIdx.x, tid = threadIdx.x;
  const float v0 = e[b*512 + tid];
  const float v1 = e[b*512 + 256 + tid];
  red[tid] = fmaxf(v0, v1);
  __syncthreads();
  for (int st = 128; st; st >>= 1) { if (tid < st) red[tid] = fmaxf(red[tid], red[tid+st]); __syncthreads(); }
  const float M = red[0];
  __syncthreads();
  const float e0 = __expf(v0 - M), e1 = __expf(v1 - M);
  red[tid] = e0 + e1;
  __syncthreads();
  for (int st = 128; st; st >>= 1) { if (tid < st) red[tid] += red[tid+st]; __syncthreads(); }
  const float inv = 1.0f / red[0];
  const float a0 = e0*inv, a1 = e1*inv;
  attn[b*512 + tid]       = a0;
  attn[b*512 + 256 + tid] = a1;
  aT[tid*64 + b]       = a0;
  aT[(256+tid)*64 + b] = a1;
}

__global__ void __launch_bounds__(256) attn_pool(const float* __restrict__ outsum,
                                                 const float* __restrict__ aT,
                                                 float* __restrict__ pooled) {
  const int tid = threadIdx.x;
  const int b = tid & 63, jj = tid >> 6;
  const int j = blockIdx.x*4 + jj;
  float acc = 0.0f;
  #pragma unroll 4
  for (int t = 0; t < 512; ++t)
    acc += aT[t*64 + b] * outsum[((size_t)t*512 + j)*64 + b];
  pooled[j*64 + b] = acc;
}

__global__ void __launch_bounds__(128) pred_kern(const float* __restrict__ pooled,
                                                 const float* __restrict__ Wo,
                                                 const float* __restrict__ bo,
                                                 float* __restrict__ out) {
  const int b = blockIdx.x, o = threadIdx.x;
  float acc = bo[o];
  const float* wr = Wo + o*512;
  #pragma unroll 4
  for (int j = 0; j < 512; j += 4) {
    const float4 w = *(const float4*)(wr + j);
    acc += w.x*pooled[(j+0)*64 + b] + w.y*pooled[(j+1)*64 + b]
         + w.z*pooled[(j+2)*64 + b] + w.w*pooled[(j+3)*64 + b];
  }
  out[b*128 + o] = acc;
}

extern "C" void kernel_launch(void* const* d_in, const int* in_sizes, int n_in,
                              void* d_out, int out_size, void* d_ws, size_t ws_size,
                              hipStream_t stream) {
  (void)in_sizes; (void)n_in; (void)out_size; (void)ws_size;
  const float* x    = (const float*)d_in[0];
  const float* Wih0 = (const float*)d_in[1];
  const float* Whh0 = (const float*)d_in[2];
  const float* b0   = (const float*)d_in[3];
  const float* Wih1 = (const float*)d_in[4];
  const float* Whh1 = (const float*)d_in[5];
  const float* b1   = (const float*)d_in[6];
  const float* Wa   = (const float*)d_in[7];
  const float* ba   = (const float*)d_in[8];
  const float* Wo   = (const float*)d_in[9];
  const float* bo   = (const float*)d_in[10];
  float* out = (float*)d_out;
  char* wsb  = (char*)d_ws;

  // zero hbuf + cstore + flags + xwflg + syn (contiguous) — per-launch reset
  hipMemsetAsync(wsb + OFF_HBUF, 0, SZ_HBUF + SZ_CST + SZ_FLG + SZ_XWF + SZ_SYN, stream);

  mega<<<dim3(2*NWG), dim3(256), FUSED_LDS, stream>>>(x, Wih0, Whh0, b0, Wih1, Whh1, b1, wsb);

  attn_logits <<<512, 256, 0, stream>>>((float*)(wsb + OFF_OUT), Wa, ba, (float*)(wsb + OFF_E));
  attn_softmax<<< 64, 256, 0, stream>>>((float*)(wsb + OFF_E), out + 8192, (float*)(wsb + OFF_AT));
  attn_pool   <<<128, 256, 0, stream>>>((float*)(wsb + OFF_OUT), (float*)(wsb + OFF_AT),
                                        (float*)(wsb + OFF_POOL));
  pred_kern   <<< 64, 128, 0, stream>>>((float*)(wsb + OFF_POOL), Wo, bo, out);
}

// Round 10
// 7300.787 us; speedup vs baseline: 1.3905x; 1.3905x over previous
//
#include <hip/hip_runtime.h>
#include <cstdint>
#include <cstddef>

#define TT 512
#define NWG 256
#define SCH0 32
#define NCH0 16
#define SCH1 16
#define NCH1 32

// ---- Workspace layout (BYTE offsets) — identical region sizes to round 6.
#define OFF_H0   0ul
#define SZ_H0    (512ul*1024ul*64ul*2ul)          /* layer0 out, bf16 (T,1024,B) 64MiB */
#define OFF_OUT  (OFF_H0 + SZ_H0)
#define SZ_OUT   (512ul*512ul*64ul*4ul)           /* l1 fwd+bwd sum fp32; ALSO l0 xw dbuf */
#define OFF_XW1  (OFF_OUT + SZ_OUT)
#define SZ_XW1   (2ul*32ul*2048ul*64ul*4ul)       /* layer1 xw double buffer, 32MiB */
#define OFF_HBUF (OFF_XW1 + SZ_XW1)
#define SZ_HBUF  (2ul*2ul*2ul*512ul*64ul*4ul)     /* [layer][pp][dir] packed-h u32 */
#define OFF_CST  (OFF_HBUF + SZ_HBUF)
#define SZ_CST   (2ul*2ul*512ul*64ul*4ul)
#define OFF_FLG  (OFF_CST + SZ_CST)
#define SZ_FLG   (2ul*2ul*512ul*128ul*4ul)        /* u32 flags [layer][dir][step][slot] */
#define OFF_E    (OFF_FLG + SZ_FLG)
#define SZ_E     (64ul*512ul*4ul)
#define OFF_AT   (OFF_E + SZ_E)
#define SZ_AT    (512ul*64ul*4ul)
#define OFF_POOL (OFF_AT + SZ_AT)
#define SZ_POOL  (512ul*64ul*4ul)

#define SZB0 (2ul*(size_t)SCH0*2048ul*64ul*4ul)   /* 33.5MB l0 xw chunk; 2 fit in SZ_OUT */
#define SZB1 (2ul*(size_t)SCH1*2048ul*64ul*4ul)   /* 16.8MB l1 xw chunk; 2 fit in SZ_XW1 */

#define FUSED_LDS 53248   /* recur 32KB; gemm mfma 48KB; 2 blocks/CU */

typedef unsigned long long u64;
typedef __attribute__((ext_vector_type(8))) short short8v;   // bf16x8 MFMA frag
typedef __attribute__((ext_vector_type(4))) float f32x4;     // MFMA C/D frag

#define AHL(p) __hip_atomic_load((p), __ATOMIC_RELAXED, __HIP_MEMORY_SCOPE_AGENT)

__device__ __forceinline__ unsigned short f2bf(float f) {   // RNE bf16
  unsigned u = __float_as_uint(f);
  u += 0x7fffu + ((u >> 16) & 1u);
  return (unsigned short)(u >> 16);
}

// ---- Unified xW GEMM tile, MFMA split-bf16 for BOTH layers.
// xw[g][b] = bias + sum_k W[g][k] X[t][k or b][...].
//  * l0 (X32 != null): K=256, X fp32 (T,B,256) -> split xb+xr at staging;
//    products Wb.xb + Wb.xr + Wr.xb (drop Wr.xr ~ 1e-10 rel) — the exact
//    3-term scheme hardware-proven in the recurrence since round 4.
//  * l1 (Xb != null): K=1024, X = h0 bf16 exact; products Wb.x + Wr.x
//    (round-6 verbatim).
// Fragment layout carried verbatim from the round-4/6-verified kernels:
// A lane(lhi,lcol) holds m=lcol (via os XOR), k=(ks*4+lhi)*8+e; C row=lhi*4+r,
// col=lcol. LDS A rows octet-XOR-swizzled -> ds_read_b128 conflict-free.
__device__ __forceinline__ void gemm_tile_mfma(const float* __restrict__ X32,
                                               const unsigned short* __restrict__ Xb,
                                               const float* __restrict__ W,
                                               const float* __restrict__ bias,
                                               float* __restrict__ xwout,
                                               int s0, int sch, int gtile, int sl, int d,
                                               unsigned short* aWb, unsigned short* aWr,
                                               unsigned short* aXb, unsigned short* aXr) {
  const int K = X32 ? 256 : 1024;
  const int tid = threadIdx.x;
  const int sg = s0 + sl;
  const int t = d ? (511 - sg) : sg;
  const int w = tid >> 6, lane = tid & 63;
  const int lhi = lane >> 4, lcol = lane & 15;
  const int g0 = gtile*128;
  const float* Wbase = W + ((size_t)d*2048 + g0)*K;

  f32x4 acc[8];
  #pragma unroll
  for (int mt = 0; mt < 8; ++mt) acc[mt] = (f32x4){0.f,0.f,0.f,0.f};

  for (int kc = 0; kc < K; kc += 64) {
    __syncthreads();
    // stage W: 128 rows x 64 k fp32 -> split-bf16, octet-swizzled [row][os*8+e]
    #pragma unroll
    for (int i = 0; i < 4; ++i) {
      const int p = i*256 + tid;
      const int row = p >> 3, o = p & 7;
      const float* src = Wbase + (size_t)row*K + kc + o*8;
      const float4 v0 = *(const float4*)(src);
      const float4 v1 = *(const float4*)(src + 4);
      const float f[8] = {v0.x,v0.y,v0.z,v0.w,v1.x,v1.y,v1.z,v1.w};
      short8v vb, vr;
      #pragma unroll
      for (int e = 0; e < 8; ++e) {
        const unsigned short hb = f2bf(f[e]);
        vb[e] = (short)hb;
        vr[e] = (short)f2bf(f[e] - __uint_as_float((unsigned)hb << 16));
      }
      const int os = o ^ (row & 7);
      *(short8v*)(aWb + (size_t)row*64 + os*8) = vb;
      *(short8v*)(aWr + (size_t)row*64 + os*8) = vr;
    }
    if (X32) {
      // stage X (l0): 64 b x 64 k fp32 -> split-bf16 pair, B-frag layout
      #pragma unroll
      for (int i = 0; i < 4; ++i) {
        const int p = i*256 + tid;
        const int bb = p >> 4, kq = p & 15;
        const float4 v = *(const float4*)(X32 + ((size_t)t*64 + bb)*256 + kc + kq*4);
        const float f[4] = {v.x, v.y, v.z, v.w};
        #pragma unroll
        for (int j = 0; j < 4; ++j) {
          const int k = kq*4 + j;
          const int o = k >> 3, e = k & 7;
          const unsigned short hb = f2bf(f[j]);
          const unsigned short hr = f2bf(f[j] - __uint_as_float((unsigned)hb << 16));
          aXb[((o*64 + bb)<<3) + e] = hb;
          aXr[((o*64 + bb)<<3) + e] = hr;
        }
      }
    } else {
      // stage X (l1): h0 bf16, round-6 verbatim (plain loads; h0 published at
      // the producing dispatch's boundary -> coherent; 16x L2 reuse)
      const unsigned short* Xbase = Xb + (size_t)t*K*64;
      #pragma unroll
      for (int i = 0; i < 4; ++i) {
        const int p = i*256 + tid;
        const int k = p >> 4, b4 = (p & 15) << 2;
        const uint2 r = *(const uint2*)(Xbase + (size_t)(kc + k)*64 + b4);
        const int o = k >> 3, e = k & 7;
        aXb[((o*64 + b4+0)<<3) + e] = (unsigned short)(r.x & 0xffffu);
        aXb[((o*64 + b4+1)<<3) + e] = (unsigned short)(r.x >> 16);
        aXb[((o*64 + b4+2)<<3) + e] = (unsigned short)(r.y & 0xffffu);
        aXb[((o*64 + b4+3)<<3) + e] = (unsigned short)(r.y >> 16);
      }
    }
    __syncthreads();
    #pragma unroll
    for (int ks = 0; ks < 2; ++ks) {
      const int xoff = (((ks*4 + lhi)*64) + w*16 + lcol)*8;
      const short8v xb = *(const short8v*)(aXb + xoff);
      #pragma unroll
      for (int mt = 0; mt < 8; ++mt) {
        const int row = mt*16 + lcol;
        const int os = (ks*4 + lhi) ^ (row & 7);
        const short8v ab = *(const short8v*)(aWb + (size_t)row*64 + os*8);
        const short8v ar = *(const short8v*)(aWr + (size_t)row*64 + os*8);
        acc[mt] = __builtin_amdgcn_mfma_f32_16x16x32_bf16(ab, xb, acc[mt], 0, 0, 0);
        if (X32) {
          const short8v xr = *(const short8v*)(aXr + xoff);
          acc[mt] = __builtin_amdgcn_mfma_f32_16x16x32_bf16(ab, xr, acc[mt], 0, 0, 0);
        }
        acc[mt] = __builtin_amdgcn_mfma_f32_16x16x32_bf16(ar, xb, acc[mt], 0, 0, 0);
      }
    }
  }
  float* op = xwout + (((size_t)d*sch + sl)*2048 + g0)*64 + w*16 + lcol;
  const float* bp = bias + d*2048 + g0;
  #pragma unroll
  for (int mt = 0; mt < 8; ++mt) {
    #pragma unroll
    for (int r = 0; r < 4; ++r) {
      const int grow = mt*16 + lhi*4 + r;
      op[(size_t)grow*64] = acc[mt][r] + bp[grow];
    }
  }
}

__device__ __forceinline__ void gemm_tile(const float* __restrict__ X32,
                                          const unsigned short* __restrict__ Xb,
                                          const float* __restrict__ W,
                                          const float* __restrict__ bias,
                                          float* __restrict__ xwout,
                                          int s0, int sch, int gtile, int sl, int d,
                                          float* lds) {
  unsigned short* aWb = (unsigned short*)lds;       // [128][64] 16KB
  unsigned short* aWr = aWb + 8192;                 // 16KB
  unsigned short* aXb = aWr + 8192;                 // [8][64][8] 8KB
  unsigned short* aXr = aXb + 4096;                 // 8KB (l0 only)
  gemm_tile_mfma(X32, Xb, W, bias, xwout, s0, sch, gtile, sl, d, aWb, aWr, aXb, aXr);
}

// standalone GEMM dispatch (layer-0 chunk 0 prologue; layer-1 chunk 0 between layers).
// layer-1 chunk 0 CANNOT be fused into the last layer-0 dispatch: every job reads h0
// rows written by the FINAL layer-0 steps -> in-dispatch race (round-1 failure).
__global__ void __launch_bounds__(256) xw_gemm(const float* __restrict__ X32,
                                               const unsigned short* __restrict__ Xb,
                                               const float* __restrict__ W,
                                               const float* __restrict__ bias,
                                               float* __restrict__ xwout,
                                               int s0, int sch) {
  __shared__ float lds_s[12288];
  gemm_tile(X32, Xb, W, bias, xwout, s0, sch, blockIdx.x, blockIdx.y, blockIdx.z, lds_s);
}

// ---- Recurrent body (round-6 VERBATIM): gates[16 m][64 b] = Whh16 x h via
// MFMA 16x16x32 bf16 split-bf16 (Wb.hb + Wb.rb + Wr.hb). Lane-local epilogue,
// 2 barriers/step, round-2 handshake (tid<128 poll + B0, Bend drain, tid0 flag).
__device__ __forceinline__ void recur_body(
    const float* __restrict__ Whh, const float* __restrict__ xw,
    char* __restrict__ wsb, int layer, int s0, int sch, float* lds)
{
  unsigned short* alds = (unsigned short*)lds;   // [2 part][16 ks][4 oct][16 slot][8 e] bf16 = 32KB

  unsigned short* h0 = (unsigned short*)(wsb + OFF_H0);
  float* outsum  = (float*)(wsb + OFF_OUT);
  unsigned* hbase = (unsigned*)(wsb + OFF_HBUF) + (size_t)layer*131072;
  float* cstore  = (float*)(wsb + OFF_CST);
  unsigned* flg  = (unsigned*)(wsb + OFF_FLG);

  const int tid = threadIdx.x;
  const int d     = blockIdx.x >> 7;
  const int slot  = blockIdx.x & 127;
  const int jbase = slot << 2;

  const int w    = tid >> 6;          // wave -> 16-batch column block
  const int lane = tid & 63;
  const int lhi  = lane >> 4;
  const int lcol = lane & 15;
  const int jj   = lhi;               // epilogue j index (C row group)
  const int b    = w*16 + lcol;       // epilogue batch (C col)

  __builtin_amdgcn_s_setprio(1);      // recurrence waves preferred over gemm waves

  // stage Whh as split-bf16 MFMA A-fragments. element (m,k) at
  // [part][k>>5][(k>>3)&3][m ^ ((k>>3)&3)][k&7]  (XOR de-conflicts b128 reads)
  for (int m = 0; m < 16; ++m) {
    const int g = m & 3, j = m >> 2;
    const float* src = Whh + ((size_t)d*2048 + g*512 + jbase + j)*512;
    for (int k = tid; k < 512; k += 256) {
      const float wv = src[k];
      const unsigned short wb = f2bf(wv);
      const unsigned short wr = f2bf(wv - __uint_as_float((unsigned)wb << 16));
      const int oct = (k >> 3) & 3;
      const int idx = (((k >> 5)*4 + oct)*16 + (m ^ oct))*8 + (k & 7);
      alds[idx] = wb;
      alds[8192 + idx] = wr;
    }
  }
  float creg = cstore[((size_t)(layer*2 + d)*512 + jbase + jj)*64 + b];
  __syncthreads();

  const unsigned fbase = (unsigned)(layer*2 + d) * 512u;

  for (int sl = 0; sl < sch; ++sl) {
    const int sg = s0 + sl;
    const int t_in = d ? (511 - sg) : sg;

    // xw preacts are h-independent: issue before the poll (latency hides there)
    const float* xwp = xw + ((size_t)(d*sch + sl)*2048 + (size_t)(jbase + jj))*64 + b;
    const float px0 = xwp[0];
    const float px1 = xwp[32768];
    const float px2 = xwp[65536];
    const float px3 = xwp[98304];

    if (sg > 0) {
      if (tid < 128) {   // proven round-2 poll: 1 flag/lane, relaxed agent
        unsigned* p = &flg[(size_t)(fbase + (unsigned)sg - 1u)*128 + tid];
        while (AHL(p) == 0u) __builtin_amdgcn_s_sleep(1);
      }
      __syncthreads();   // B0
    }

    const u64* hsrc = (const u64*)(hbase + ((sg & 1)*2 + d)*32768);

    // B operand ring: per ks, 4 u64 = 8 packed dwords = elements e0..7 for col b.
    u64 ring[8][4];
    #pragma unroll
    for (int ks = 0; ks < 8; ++ks) {
      const size_t hb0 = (size_t)((ks*4 + lhi)*4)*64 + b;
      ring[ks][0] = AHL(hsrc + hb0);
      ring[ks][1] = AHL(hsrc + hb0 + 64);
      ring[ks][2] = AHL(hsrc + hb0 + 128);
      ring[ks][3] = AHL(hsrc + hb0 + 192);
    }

    f32x4 acc = {0.f, 0.f, 0.f, 0.f};
    #pragma unroll
    for (int ks = 0; ks < 16; ++ks) {
      const u64 q0 = ring[ks & 7][0], q1 = ring[ks & 7][1];
      const u64 q2 = ring[ks & 7][2], q3 = ring[ks & 7][3];
      if (ks < 8) {
        const size_t hb2 = (size_t)(((ks + 8)*4 + lhi)*4)*64 + b;
        ring[ks][0] = AHL(hsrc + hb2);
        ring[ks][1] = AHL(hsrc + hb2 + 64);
        ring[ks][2] = AHL(hsrc + hb2 + 128);
        ring[ks][3] = AHL(hsrc + hb2 + 192);
      }
      // unpack packed (hb<<16)|rb dwords into value/residual bf16 fragments
      union { unsigned u[4]; short8v v; } hb, rb;
      hb.u[0] = __builtin_amdgcn_perm((unsigned)(q0 >> 32), (unsigned)q0, 0x07060302u);
      rb.u[0] = __builtin_amdgcn_perm((unsigned)(q0 >> 32), (unsigned)q0, 0x05040100u);
      hb.u[1] = __builtin_amdgcn_perm((unsigned)(q1 >> 32), (unsigned)q1, 0x07060302u);
      rb.u[1] = __builtin_amdgcn_perm((unsigned)(q1 >> 32), (unsigned)q1, 0x05040100u);
      hb.u[2] = __builtin_amdgcn_perm((unsigned)(q2 >> 32), (unsigned)q2, 0x07060302u);
      rb.u[2] = __builtin_amdgcn_perm((unsigned)(q2 >> 32), (unsigned)q2, 0x05040100u);
      hb.u[3] = __builtin_amdgcn_perm((unsigned)(q3 >> 32), (unsigned)q3, 0x07060302u);
      rb.u[3] = __builtin_amdgcn_perm((unsigned)(q3 >> 32), (unsigned)q3, 0x05040100u);
      const int abase = ((ks*4 + lhi)*16 + (lcol ^ lhi))*8;
      const short8v ab = *(const short8v*)(alds + abase);
      const short8v ar = *(const short8v*)(alds + 8192 + abase);
      acc = __builtin_amdgcn_mfma_f32_16x16x32_bf16(ab, hb.v, acc, 0, 0, 0);
      acc = __builtin_amdgcn_mfma_f32_16x16x32_bf16(ab, rb.v, acc, 0, 0, 0);
      acc = __builtin_amdgcn_mfma_f32_16x16x32_bf16(ar, hb.v, acc, 0, 0, 0);
      // dropped Wr*rb term: ~4e-6 relative
    }

    // epilogue: lane-local gates (acc[r] = gate r of j = jbase+jj, batch b)
    const float pi = acc[0] + px0;
    const float pf = acc[1] + px1;
    const float pg = acc[2] + px2;
    const float po = acc[3] + px3;
    const float iv = 1.0f/(1.0f + __expf(-pi));
    const float fv = 1.0f/(1.0f + __expf(-pf));
    const float gv = tanhf(pg);
    const float ov = 1.0f/(1.0f + __expf(-po));
    float cc2 = fv*creg + iv*gv;
    cc2 = fminf(fmaxf(cc2, -100.0f), 100.0f);
    creg = cc2;
    const float h = ov*tanhf(cc2);

    const unsigned short hb16 = f2bf(h);
    const unsigned short rb16 = f2bf(h - __uint_as_float((unsigned)hb16 << 16));
    const unsigned hpk = ((unsigned)hb16 << 16) | (unsigned)rb16;
    unsigned* hout = hbase + (((sg & 1) ^ 1)*2 + d)*32768;
    const int kj = jbase + jj;
    __hip_atomic_store(hout + ((size_t)(kj >> 1)*128 + b*2 + (kj & 1)), hpk,
                       __ATOMIC_RELAXED, __HIP_MEMORY_SCOPE_AGENT);

    __syncthreads();   // Bend: drains each wave's vmcnt -> h stores ACKed
    if (tid == 0)
      __hip_atomic_store(&flg[(size_t)(fbase + (unsigned)sg)*128 + slot], 1u,
                         __ATOMIC_RELAXED, __HIP_MEMORY_SCOPE_AGENT);
    // deferred: consumed only across dispatch boundaries -> off the critical
    // edge; their ACK folds into the NEXT step's Bend (poll interval >> ACK).
    if (layer == 0) {
      h0[(size_t)t_in*65536 + (size_t)(d*512 + kj)*64 + b] = hb16;
    } else {
      atomicAdd(&outsum[(size_t)t_in*32768 + (size_t)kj*64 + b], h);
    }
  }
  cstore[((size_t)(layer*2 + d)*512 + jbase + jj)*64 + b] = creg;
}

// ---- Fused dispatch: blocks 0..255 = recurrence; blocks 256..511 = next-chunk GEMM.
// GEMM half never polls -> no deadlock; any two WGs co-reside (<=52KB LDS each).
__global__ void __launch_bounds__(256, 2) fused_step(
    const float* __restrict__ Whh, const float* __restrict__ xw_cur,
    float* __restrict__ xw_next,
    const float* __restrict__ gX32, const unsigned short* __restrict__ gXb,
    const float* __restrict__ gW, const float* __restrict__ gB,
    char* __restrict__ wsb,
    int rlayer, int rs0, int rsch,
    int gs0, int gsch, int gnjobs)
{
  extern __shared__ float lds[];
  if (blockIdx.x < NWG) {
    recur_body(Whh, xw_cur, wsb, rlayer, rs0, rsch, lds);
  } else {
    const int wg = blockIdx.x - NWG;
    const int half = gnjobs >> 1;
    for (int job = wg; job < gnjobs; job += NWG) {
      const int dd  = (job >= half) ? 1 : 0;
      const int rem = job - (dd ? half : 0);
      const int sl  = rem >> 4;
      const int gt  = rem & 15;
      gemm_tile(gX32, gXb, gW, gB, xw_next, gs0, gsch, gt, sl, dd, lds);
    }
  }
}

// ---- attention / output chain (unchanged) ----
__global__ void __launch_bounds__(256) attn_logits(const float* __restrict__ outsum,
                                                   const float* __restrict__ Wa,
                                                   const float* __restrict__ ba,
                                                   float* __restrict__ e) {
  __shared__ float part[4*64];
  const int t = blockIdx.x;
  const int b = threadIdx.x & 63, jq = threadIdx.x >> 6;
  const float* base = outsum + (size_t)t * 512 * 64;
  float acc = 0.0f;
  for (int j = jq*128; j < jq*128 + 128; ++j)
    acc += base[j*64 + b] * Wa[j];
  part[jq*64 + b] = acc;
  __syncthreads();
  if (threadIdx.x < 64) {
    const int bb = threadIdx.x;
    e[bb*512 + t] = part[0*64+bb] + part[1*64+bb] + part[2*64+bb] + part[3*64+bb] + ba[0];
  }
}

__global__ void __launch_bounds__(256) attn_softmax(const float* __restrict__ e,
                                                    float* __restrict__ attn,
                                                    float* __restrict__ aT) {
  __shared__ float red[256];
  const int b = blockIdx.x, tid = threadIdx.x;
  const float v0 = e[b*512 + tid];
  const float v1 = e[b*512 + 256 + tid];
  red[tid] = fmaxf(v0, v1);
  __syncthreads();
  for (int st = 128; st; st >>= 1) { if (tid < st) red[tid] = fmaxf(red[tid], red[tid+st]); __syncthreads(); }
  const float M = red[0];
  __syncthreads();
  const float e0 = __expf(v0 - M), e1 = __expf(v1 - M);
  red[tid] = e0 + e1;
  __syncthreads();
  for (int st = 128; st; st >>= 1) { if (tid < st) red[tid] += red[tid+st]; __syncthreads(); }
  const float inv = 1.0f / red[0];
  const float a0 = e0*inv, a1 = e1*inv;
  attn[b*512 + tid]       = a0;
  attn[b*512 + 256 + tid] = a1;
  aT[tid*64 + b]       = a0;
  aT[(256+tid)*64 + b] = a1;
}

__global__ void __launch_bounds__(256) attn_pool(const float* __restrict__ outsum,
                                                 const float* __restrict__ aT,
                                                 float* __restrict__ pooled) {
  const int tid = threadIdx.x;
  const int b = tid & 63, jj = tid >> 6;
  const int j = blockIdx.x*4 + jj;
  float acc = 0.0f;
  #pragma unroll 4
  for (int t = 0; t < 512; ++t)
    acc += aT[t*64 + b] * outsum[((size_t)t*512 + j)*64 + b];
  pooled[j*64 + b] = acc;
}

__global__ void __launch_bounds__(128) pred_kern(const float* __restrict__ pooled,
                                                 const float* __restrict__ Wo,
                                                 const float* __restrict__ bo,
                                                 float* __restrict__ out) {
  const int b = blockIdx.x, o = threadIdx.x;
  float acc = bo[o];
  const float* wr = Wo + o*512;
  #pragma unroll 4
  for (int j = 0; j < 512; j += 4) {
    const float4 w = *(const float4*)(wr + j);
    acc += w.x*pooled[(j+0)*64 + b] + w.y*pooled[(j+1)*64 + b]
         + w.z*pooled[(j+2)*64 + b] + w.w*pooled[(j+3)*64 + b];
  }
  out[b*128 + o] = acc;
}

extern "C" void kernel_launch(void* const* d_in, const int* in_sizes, int n_in,
                              void* d_out, int out_size, void* d_ws, size_t ws_size,
                              hipStream_t stream) {
  (void)in_sizes; (void)n_in; (void)out_size; (void)ws_size;
  const float* x    = (const float*)d_in[0];
  const float* Wih0 = (const float*)d_in[1];
  const float* Whh0 = (const float*)d_in[2];
  const float* b0   = (const float*)d_in[3];
  const float* Wih1 = (const float*)d_in[4];
  const float* Whh1 = (const float*)d_in[5];
  const float* b1   = (const float*)d_in[6];
  const float* Wa   = (const float*)d_in[7];
  const float* ba   = (const float*)d_in[8];
  const float* Wo   = (const float*)d_in[9];
  const float* bo   = (const float*)d_in[10];
  float* out = (float*)d_out;
  char* wsb  = (char*)d_ws;

  // zero hbuf + cstore + flags (contiguous)
  hipMemsetAsync(wsb + OFF_HBUF, 0, SZ_HBUF + SZ_CST + SZ_FLG, stream);

  float* xw0[2] = { (float*)(wsb + OFF_OUT), (float*)(wsb + OFF_OUT + SZB0) };
  float* xw1[2] = { (float*)(wsb + OFF_XW1), (float*)(wsb + OFF_XW1 + SZB1) };
  const unsigned short* h0p = (const unsigned short*)(wsb + OFF_H0);

  // layer-0 chunk-0 xw prologue (MFMA split-bf16 path)
  xw_gemm<<<dim3(16, SCH0, 2), 256, 0, stream>>>(x, nullptr, Wih0, b0, xw0[0], 0, SCH0);

  // layer 0: fused recurrence + next-chunk GEMM (last dispatch runs no gemm)
  for (int c = 0; c < NCH0; ++c) {
    const bool last = (c == NCH0 - 1);
    fused_step<<<dim3(2*NWG), dim3(256), FUSED_LDS, stream>>>(
        Whh0, xw0[c & 1], xw0[(c + 1) & 1],
        x, nullptr, Wih0, b0,
        wsb, 0, c*SCH0, SCH0,
        (c + 1)*SCH0, SCH0, last ? 0 : 16*SCH0*2);
  }

  // layer-1 chunk-0 xw (needs ALL of h0 -> standalone, dispatch-ordered)
  xw_gemm<<<dim3(16, SCH1, 2), 256, 0, stream>>>(nullptr, h0p, Wih1, b1, xw1[0], 0, SCH1);

  // outsum becomes live now; zero it (xw0 double buffer no longer needed)
  hipMemsetAsync(wsb + OFF_OUT, 0, SZ_OUT, stream);

  // layer 1
  for (int c = 0; c < NCH1; ++c) {
    const bool last = (c == NCH1 - 1);
    fused_step<<<dim3(2*NWG), dim3(256), FUSED_LDS, stream>>>(
        Whh1, xw1[c & 1], xw1[(c + 1) & 1],
        nullptr, h0p, Wih1, b1,
        wsb, 1, c*SCH1, SCH1,
        (c + 1)*SCH1, SCH1, last ? 0 : 16*SCH1*2);
  }

  attn_logits <<<512, 256, 0, stream>>>((float*)(wsb + OFF_OUT), Wa, ba, (float*)(wsb + OFF_E));
  attn_softmax<<< 64, 256, 0, stream>>>((float*)(wsb + OFF_E), out + 8192, (float*)(wsb + OFF_AT));
  attn_pool   <<<128, 256, 0, stream>>>((float*)(wsb + OFF_OUT), (float*)(wsb + OFF_AT),
                                        (float*)(wsb + OFF_POOL));
  pred_kern   <<< 64, 128, 0, stream>>>((float*)(wsb + OFF_POOL), Wo, bo, out);
}

// Round 11
// 6163.469 us; speedup vs baseline: 1.6471x; 1.1845x over previous
//
#include <hip/hip_runtime.h>
#include <cstdint>
#include <cstddef>

#define TT 512
#define NWG 256
#define SCH0 32
#define NCH0 16
#define SCH1 16
#define NCH1 32

// ---- Workspace layout (BYTE offsets) — identical region sizes to round 6/10.
#define OFF_H0   0ul
#define SZ_H0    (512ul*1024ul*64ul*2ul)          /* layer0 out, bf16 (T,1024,B) 64MiB */
#define OFF_OUT  (OFF_H0 + SZ_H0)
#define SZ_OUT   (512ul*512ul*64ul*4ul)           /* l1 fwd+bwd sum fp32; ALSO l0 xw dbuf */
#define OFF_XW1  (OFF_OUT + SZ_OUT)
#define SZ_XW1   (2ul*32ul*2048ul*64ul*4ul)       /* layer1 xw double buffer, 32MiB */
#define OFF_HBUF (OFF_XW1 + SZ_XW1)
#define SZ_HBUF  (2ul*2ul*2ul*512ul*64ul*4ul)     /* [layer][pp][dir] packed-h u32 */
#define OFF_CST  (OFF_HBUF + SZ_HBUF)
#define SZ_CST   (2ul*2ul*512ul*64ul*4ul)
#define OFF_FLG  (OFF_CST + SZ_CST)
#define SZ_FLG   (2ul*2ul*512ul*128ul*4ul)        /* u32 flags [layer][dir][step][bg*64+slot] */
#define OFF_E    (OFF_FLG + SZ_FLG)
#define SZ_E     (64ul*512ul*4ul)
#define OFF_AT   (OFF_E + SZ_E)
#define SZ_AT    (512ul*64ul*4ul)
#define OFF_POOL (OFF_AT + SZ_AT)
#define SZ_POOL  (512ul*64ul*4ul)

#define SZB0 (2ul*(size_t)SCH0*2048ul*64ul*4ul)   /* 33.5MB l0 xw chunk; 2 fit in SZ_OUT */
#define SZB1 (2ul*(size_t)SCH1*2048ul*64ul*4ul)   /* 16.8MB l1 xw chunk; 2 fit in SZ_XW1 */

#define FUSED_LDS 69632   /* recur: 64KB A-frags + 4KB exchange; gemm 48KB; 2 blocks/CU */

typedef unsigned long long u64;
typedef __attribute__((ext_vector_type(8))) short short8v;   // bf16x8 MFMA frag
typedef __attribute__((ext_vector_type(4))) float f32x4;     // MFMA C/D frag

#define AHL(p) __hip_atomic_load((p), __ATOMIC_RELAXED, __HIP_MEMORY_SCOPE_AGENT)

__device__ __forceinline__ unsigned short f2bf(float f) {   // RNE bf16
  unsigned u = __float_as_uint(f);
  u += 0x7fffu + ((u >> 16) & 1u);
  return (unsigned short)(u >> 16);
}

// ---- Unified xW GEMM tile, MFMA split-bf16 for BOTH layers (round-10 verbatim).
__device__ __forceinline__ void gemm_tile_mfma(const float* __restrict__ X32,
                                               const unsigned short* __restrict__ Xb,
                                               const float* __restrict__ W,
                                               const float* __restrict__ bias,
                                               float* __restrict__ xwout,
                                               int s0, int sch, int gtile, int sl, int d,
                                               unsigned short* aWb, unsigned short* aWr,
                                               unsigned short* aXb, unsigned short* aXr) {
  const int K = X32 ? 256 : 1024;
  const int tid = threadIdx.x;
  const int sg = s0 + sl;
  const int t = d ? (511 - sg) : sg;
  const int w = tid >> 6, lane = tid & 63;
  const int lhi = lane >> 4, lcol = lane & 15;
  const int g0 = gtile*128;
  const float* Wbase = W + ((size_t)d*2048 + g0)*K;

  f32x4 acc[8];
  #pragma unroll
  for (int mt = 0; mt < 8; ++mt) acc[mt] = (f32x4){0.f,0.f,0.f,0.f};

  for (int kc = 0; kc < K; kc += 64) {
    __syncthreads();
    #pragma unroll
    for (int i = 0; i < 4; ++i) {
      const int p = i*256 + tid;
      const int row = p >> 3, o = p & 7;
      const float* src = Wbase + (size_t)row*K + kc + o*8;
      const float4 v0 = *(const float4*)(src);
      const float4 v1 = *(const float4*)(src + 4);
      const float f[8] = {v0.x,v0.y,v0.z,v0.w,v1.x,v1.y,v1.z,v1.w};
      short8v vb, vr;
      #pragma unroll
      for (int e = 0; e < 8; ++e) {
        const unsigned short hb = f2bf(f[e]);
        vb[e] = (short)hb;
        vr[e] = (short)f2bf(f[e] - __uint_as_float((unsigned)hb << 16));
      }
      const int os = o ^ (row & 7);
      *(short8v*)(aWb + (size_t)row*64 + os*8) = vb;
      *(short8v*)(aWr + (size_t)row*64 + os*8) = vr;
    }
    if (X32) {
      #pragma unroll
      for (int i = 0; i < 4; ++i) {
        const int p = i*256 + tid;
        const int bb = p >> 4, kq = p & 15;
        const float4 v = *(const float4*)(X32 + ((size_t)t*64 + bb)*256 + kc + kq*4);
        const float f[4] = {v.x, v.y, v.z, v.w};
        #pragma unroll
        for (int j = 0; j < 4; ++j) {
          const int k = kq*4 + j;
          const int o = k >> 3, e = k & 7;
          const unsigned short hb = f2bf(f[j]);
          const unsigned short hr = f2bf(f[j] - __uint_as_float((unsigned)hb << 16));
          aXb[((o*64 + bb)<<3) + e] = hb;
          aXr[((o*64 + bb)<<3) + e] = hr;
        }
      }
    } else {
      const unsigned short* Xbase = Xb + (size_t)t*K*64;
      #pragma unroll
      for (int i = 0; i < 4; ++i) {
        const int p = i*256 + tid;
        const int k = p >> 4, b4 = (p & 15) << 2;
        const uint2 r = *(const uint2*)(Xbase + (size_t)(kc + k)*64 + b4);
        const int o = k >> 3, e = k & 7;
        aXb[((o*64 + b4+0)<<3) + e] = (unsigned short)(r.x & 0xffffu);
        aXb[((o*64 + b4+1)<<3) + e] = (unsigned short)(r.x >> 16);
        aXb[((o*64 + b4+2)<<3) + e] = (unsigned short)(r.y & 0xffffu);
        aXb[((o*64 + b4+3)<<3) + e] = (unsigned short)(r.y >> 16);
      }
    }
    __syncthreads();
    #pragma unroll
    for (int ks = 0; ks < 2; ++ks) {
      const int xoff = (((ks*4 + lhi)*64) + w*16 + lcol)*8;
      const short8v xb = *(const short8v*)(aXb + xoff);
      #pragma unroll
      for (int mt = 0; mt < 8; ++mt) {
        const int row = mt*16 + lcol;
        const int os = (ks*4 + lhi) ^ (row & 7);
        const short8v ab = *(const short8v*)(aWb + (size_t)row*64 + os*8);
        const short8v ar = *(const short8v*)(aWr + (size_t)row*64 + os*8);
        acc[mt] = __builtin_amdgcn_mfma_f32_16x16x32_bf16(ab, xb, acc[mt], 0, 0, 0);
        if (X32) {
          const short8v xr = *(const short8v*)(aXr + xoff);
          acc[mt] = __builtin_amdgcn_mfma_f32_16x16x32_bf16(ab, xr, acc[mt], 0, 0, 0);
        }
        acc[mt] = __builtin_amdgcn_mfma_f32_16x16x32_bf16(ar, xb, acc[mt], 0, 0, 0);
      }
    }
  }
  float* op = xwout + (((size_t)d*sch + sl)*2048 + g0)*64 + w*16 + lcol;
  const float* bp = bias + d*2048 + g0;
  #pragma unroll
  for (int mt = 0; mt < 8; ++mt) {
    #pragma unroll
    for (int r = 0; r < 4; ++r) {
      const int grow = mt*16 + lhi*4 + r;
      op[(size_t)grow*64] = acc[mt][r] + bp[grow];
    }
  }
}

__device__ __forceinline__ void gemm_tile(const float* __restrict__ X32,
                                          const unsigned short* __restrict__ Xb,
                                          const float* __restrict__ W,
                                          const float* __restrict__ bias,
                                          float* __restrict__ xwout,
                                          int s0, int sch, int gtile, int sl, int d,
                                          float* lds) {
  unsigned short* aWb = (unsigned short*)lds;       // [128][64] 16KB
  unsigned short* aWr = aWb + 8192;                 // 16KB
  unsigned short* aXb = aWr + 8192;                 // [8][64][8] 8KB
  unsigned short* aXr = aXb + 4096;                 // 8KB (l0 only)
  gemm_tile_mfma(X32, Xb, W, bias, xwout, s0, sch, gtile, sl, d, aWb, aWr, aXb, aXr);
}

// standalone GEMM dispatch (layer-0 chunk 0 prologue; layer-1 chunk 0 between layers).
__global__ void __launch_bounds__(256) xw_gemm(const float* __restrict__ X32,
                                               const unsigned short* __restrict__ Xb,
                                               const float* __restrict__ W,
                                               const float* __restrict__ bias,
                                               float* __restrict__ xwout,
                                               int s0, int sch) {
  __shared__ float lds_s[12288];
  gemm_tile(X32, Xb, W, bias, xwout, s0, sch, blockIdx.x, blockIdx.y, blockIdx.z, lds_s);
}

// ---- Recurrent body, ROUND-11 repartition: per direction, 64 slots x 8 j x
// 2 independent batch-group chains of 32 cols (bg). Each WG: 32 gate-rows x
// 32 cols, K=512. Waves: (kh = K-half, cw = col-half); each wave computes
// BOTH 16-row tiles over its K-half (reads h once for its 16 cols x 256 k),
// then a 4KB LDS exchange merges K-halves. Halves fabric h-traffic per step
// (each WG reads 64KB vs 128KB) and halves flag fan-in (64 vs 128).
// Handshake mechanics = proven round-2 pattern (poll + B0, Bend drain, tid0
// flag). hbuf/flag/xw/cstore/h0 layouts unchanged (keyed by (j,b)).
__device__ __forceinline__ void recur_body(
    const float* __restrict__ Whh, const float* __restrict__ xw,
    char* __restrict__ wsb, int layer, int s0, int sch, float* lds)
{
  unsigned short* alds = (unsigned short*)lds;   // 8 blocks x 4096 u16 = 64KB
                                                 // block((rw*2+kh)*2+part): [ks2][oct][16][8]
  float4* red4 = (float4*)(lds + 16384);         // [4 slots][64 lanes] f32x4 = 4KB

  unsigned short* h0 = (unsigned short*)(wsb + OFF_H0);
  float* outsum  = (float*)(wsb + OFF_OUT);
  unsigned* hbase = (unsigned*)(wsb + OFF_HBUF) + (size_t)layer*131072;
  float* cstore  = (float*)(wsb + OFF_CST);
  unsigned* flg  = (unsigned*)(wsb + OFF_FLG);

  const int tid  = threadIdx.x;
  const int d    = blockIdx.x >> 7;
  const int bg   = (blockIdx.x >> 6) & 1;   // batch-group: independent chain
  const int slot = blockIdx.x & 63;         // j in [slot*8, slot*8+8)

  const int w    = tid >> 6;
  const int lane = tid & 63;
  const int kh   = w >> 1;                  // K-half of this wave
  const int cw   = w & 1;                   // col-half of this wave
  const int lhi  = lane >> 4;
  const int lcol = lane & 15;
  const int jown = slot*8 + kh*4 + lhi;     // j of the tile this wave OWNS (rw==kh)
  const int bidx = bg*32 + cw*16 + lcol;    // dir-wide batch col

  __builtin_amdgcn_s_setprio(1);

  // stage Whh 32 rows as split-bf16 A-frags: row-block rw (16 rows, r16=jj*4+g),
  // K-half khs; inner layout + r16^oct swizzle proven r4-r10.
  for (int rw = 0; rw < 2; ++rw) {
    for (int r16 = 0; r16 < 16; ++r16) {
      const int g = r16 & 3, jj = r16 >> 2;
      const float* src = Whh + ((size_t)d*2048 + g*512 + slot*8 + rw*4 + jj)*512;
      for (int k = tid; k < 512; k += 256) {
        const float wv = src[k];
        const unsigned short wb = f2bf(wv);
        const unsigned short wr = f2bf(wv - __uint_as_float((unsigned)wb << 16));
        const int khs = k >> 8, kl = k & 255;
        const int ks2 = kl >> 5, oct = (kl >> 3) & 3, e = kl & 7;
        const int idx = ((ks2*4 + oct)*16 + (r16 ^ oct))*8 + e;
        unsigned short* blk = alds + (size_t)((rw*2 + khs)*2)*4096;
        blk[idx] = wb;          // part 0
        blk[4096 + idx] = wr;   // part 1
      }
    }
  }
  float creg = cstore[((size_t)(layer*2 + d)*512 + jown)*64 + bidx];
  __syncthreads();

  const unsigned fbase = (unsigned)(layer*2 + d) * 512u;
  const unsigned short* a0b = alds + (size_t)(kh*2)*4096;        // tile rw=0, my K-half
  const unsigned short* a1b = alds + (size_t)((4 + kh*2))*4096;  // tile rw=1, my K-half

  for (int sl = 0; sl < sch; ++sl) {
    const int sg = s0 + sl;
    const int t_in = d ? (511 - sg) : sg;

    // xw preacts are h-independent: issue before the poll (latency hides there)
    const float* xwp = xw + ((size_t)(d*sch + sl)*2048 + (size_t)jown)*64 + bidx;
    const float px0 = xwp[0];
    const float px1 = xwp[32768];
    const float px2 = xwp[65536];
    const float px3 = xwp[98304];

    if (sg > 0) {
      if (tid < 64) {   // poll only my batch-group's 64 producer flags
        unsigned* p = &flg[(size_t)(fbase + (unsigned)sg - 1u)*128 + bg*64 + tid];
        while (AHL(p) == 0u) __builtin_amdgcn_s_sleep(1);
      }
      __syncthreads();   // B0
    }

    const u64* hsrc = (const u64*)(hbase + ((sg & 1)*2 + d)*32768);

    // h loads: this wave reads ONLY its K-half x its 16 cols (16KB/wave).
    // 4-deep ring over 8 k-groups, proven round-4 rotate pattern.
    u64 ring[4][4];
    #pragma unroll
    for (int ks = 0; ks < 4; ++ks) {
      const int g8 = kh*32 + ks*4 + lhi;
      const size_t hb0 = (size_t)(g8*4)*64 + bidx;
      ring[ks][0] = AHL(hsrc + hb0);
      ring[ks][1] = AHL(hsrc + hb0 + 64);
      ring[ks][2] = AHL(hsrc + hb0 + 128);
      ring[ks][3] = AHL(hsrc + hb0 + 192);
    }

    f32x4 acc0 = {0.f,0.f,0.f,0.f};   // tile rw=0 partial (my K-half)
    f32x4 acc1 = {0.f,0.f,0.f,0.f};   // tile rw=1 partial
    #pragma unroll
    for (int ks = 0; ks < 8; ++ks) {
      const u64 q0 = ring[ks & 3][0], q1 = ring[ks & 3][1];
      const u64 q2 = ring[ks & 3][2], q3 = ring[ks & 3][3];
      if (ks < 4) {
        const int g8 = kh*32 + (ks + 4)*4 + lhi;
        const size_t hb2 = (size_t)(g8*4)*64 + bidx;
        ring[ks][0] = AHL(hsrc + hb2);
        ring[ks][1] = AHL(hsrc + hb2 + 64);
        ring[ks][2] = AHL(hsrc + hb2 + 128);
        ring[ks][3] = AHL(hsrc + hb2 + 192);
      }
      union { unsigned u[4]; short8v v; } hb, rb;
      hb.u[0] = __builtin_amdgcn_perm((unsigned)(q0 >> 32), (unsigned)q0, 0x07060302u);
      rb.u[0] = __builtin_amdgcn_perm((unsigned)(q0 >> 32), (unsigned)q0, 0x05040100u);
      hb.u[1] = __builtin_amdgcn_perm((unsigned)(q1 >> 32), (unsigned)q1, 0x07060302u);
      rb.u[1] = __builtin_amdgcn_perm((unsigned)(q1 >> 32), (unsigned)q1, 0x05040100u);
      hb.u[2] = __builtin_amdgcn_perm((unsigned)(q2 >> 32), (unsigned)q2, 0x07060302u);
      rb.u[2] = __builtin_amdgcn_perm((unsigned)(q2 >> 32), (unsigned)q2, 0x05040100u);
      hb.u[3] = __builtin_amdgcn_perm((unsigned)(q3 >> 32), (unsigned)q3, 0x07060302u);
      rb.u[3] = __builtin_amdgcn_perm((unsigned)(q3 >> 32), (unsigned)q3, 0x05040100u);
      const int inner = ((ks*4 + lhi)*16 + (lcol ^ lhi))*8;
      const short8v ab0 = *(const short8v*)(a0b + inner);
      const short8v ar0 = *(const short8v*)(a0b + 4096 + inner);
      acc0 = __builtin_amdgcn_mfma_f32_16x16x32_bf16(ab0, hb.v, acc0, 0, 0, 0);
      acc0 = __builtin_amdgcn_mfma_f32_16x16x32_bf16(ab0, rb.v, acc0, 0, 0, 0);
      acc0 = __builtin_amdgcn_mfma_f32_16x16x32_bf16(ar0, hb.v, acc0, 0, 0, 0);
      const short8v ab1 = *(const short8v*)(a1b + inner);
      const short8v ar1 = *(const short8v*)(a1b + 4096 + inner);
      acc1 = __builtin_amdgcn_mfma_f32_16x16x32_bf16(ab1, hb.v, acc1, 0, 0, 0);
      acc1 = __builtin_amdgcn_mfma_f32_16x16x32_bf16(ab1, rb.v, acc1, 0, 0, 0);
      acc1 = __builtin_amdgcn_mfma_f32_16x16x32_bf16(ar1, hb.v, acc1, 0, 0, 0);
    }

    // cross-wave K-half exchange: give the non-owned tile to its owner wave.
    // red slot = rw*2 + cw. Writes/reads are b128, lane-consecutive -> conflict-free.
    if (kh == 0) red4[(size_t)(2 + cw)*64 + lane] = make_float4(acc1[0],acc1[1],acc1[2],acc1[3]);
    else         red4[(size_t)(0 + cw)*64 + lane] = make_float4(acc0[0],acc0[1],acc0[2],acc0[3]);
    __syncthreads();   // Bx
    f32x4 own = (kh == 0) ? acc0 : acc1;
    {
      const float4 p = red4[(size_t)(kh*2 + cw)*64 + lane];
      own[0] += p.x; own[1] += p.y; own[2] += p.z; own[3] += p.w;
    }

    // epilogue: lane-local gates (own[r] = gate r of j = jown, batch bidx)
    const float pi = own[0] + px0;
    const float pf = own[1] + px1;
    const float pg = own[2] + px2;
    const float po = own[3] + px3;
    const float iv = 1.0f/(1.0f + __expf(-pi));
    const float fv = 1.0f/(1.0f + __expf(-pf));
    const float gv = tanhf(pg);
    const float ov = 1.0f/(1.0f + __expf(-po));
    float cc2 = fv*creg + iv*gv;
    cc2 = fminf(fmaxf(cc2, -100.0f), 100.0f);
    creg = cc2;
    const float h = ov*tanhf(cc2);

    const unsigned short hb16 = f2bf(h);
    const unsigned short rb16 = f2bf(h - __uint_as_float((unsigned)hb16 << 16));
    const unsigned hpk = ((unsigned)hb16 << 16) | (unsigned)rb16;
    unsigned* hout = hbase + (((sg & 1) ^ 1)*2 + d)*32768;
    __hip_atomic_store(hout + ((size_t)(jown >> 1)*128 + bidx*2 + (jown & 1)), hpk,
                       __ATOMIC_RELAXED, __HIP_MEMORY_SCOPE_AGENT);

    __syncthreads();   // Bend: drains each wave's vmcnt -> h stores ACKed; guards red4
    if (tid == 0)
      __hip_atomic_store(&flg[(size_t)(fbase + (unsigned)sg)*128 + bg*64 + slot], 1u,
                         __ATOMIC_RELAXED, __HIP_MEMORY_SCOPE_AGENT);
    // deferred: consumed only across dispatch boundaries -> off critical edge
    if (layer == 0) {
      h0[(size_t)t_in*65536 + (size_t)(d*512 + jown)*64 + bidx] = hb16;
    } else {
      atomicAdd(&outsum[(size_t)t_in*32768 + (size_t)jown*64 + bidx], h);
    }
  }
  cstore[((size_t)(layer*2 + d)*512 + jown)*64 + bidx] = creg;
}

// ---- Fused dispatch: blocks 0..255 = recurrence; blocks 256..511 = next-chunk GEMM.
// GEMM half never polls -> no deadlock; any two WGs co-reside (68KB LDS, 2/CU).
__global__ void __launch_bounds__(256, 2) fused_step(
    const float* __restrict__ Whh, const float* __restrict__ xw_cur,
    float* __restrict__ xw_next,
    const float* __restrict__ gX32, const unsigned short* __restrict__ gXb,
    const float* __restrict__ gW, const float* __restrict__ gB,
    char* __restrict__ wsb,
    int rlayer, int rs0, int rsch,
    int gs0, int gsch, int gnjobs)
{
  extern __shared__ float lds[];
  if (blockIdx.x < NWG) {
    recur_body(Whh, xw_cur, wsb, rlayer, rs0, rsch, lds);
  } else {
    const int wg = blockIdx.x - NWG;
    const int half = gnjobs >> 1;
    for (int job = wg; job < gnjobs; job += NWG) {
      const int dd  = (job >= half) ? 1 : 0;
      const int rem = job - (dd ? half : 0);
      const int sl  = rem >> 4;
      const int gt  = rem & 15;
      gemm_tile(gX32, gXb, gW, gB, xw_next, gs0, gsch, gt, sl, dd, lds);
    }
  }
}

// ---- attention / output chain (unchanged) ----
__global__ void __launch_bounds__(256) attn_logits(const float* __restrict__ outsum,
                                                   const float* __restrict__ Wa,
                                                   const float* __restrict__ ba,
                                                   float* __restrict__ e) {
  __shared__ float part[4*64];
  const int t = blockIdx.x;
  const int b = threadIdx.x & 63, jq = threadIdx.x >> 6;
  const float* base = outsum + (size_t)t * 512 * 64;
  float acc = 0.0f;
  for (int j = jq*128; j < jq*128 + 128; ++j)
    acc += base[j*64 + b] * Wa[j];
  part[jq*64 + b] = acc;
  __syncthreads();
  if (threadIdx.x < 64) {
    const int bb = threadIdx.x;
    e[bb*512 + t] = part[0*64+bb] + part[1*64+bb] + part[2*64+bb] + part[3*64+bb] + ba[0];
  }
}

__global__ void __launch_bounds__(256) attn_softmax(const float* __restrict__ e,
                                                    float* __restrict__ attn,
                                                    float* __restrict__ aT) {
  __shared__ float red[256];
  const int b = blockIdx.x, tid = threadIdx.x;
  const float v0 = e[b*512 + tid];
  const float v1 = e[b*512 + 256 + tid];
  red[tid] = fmaxf(v0, v1);
  __syncthreads();
  for (int st = 128; st; st >>= 1) { if (tid < st) red[tid] = fmaxf(red[tid], red[tid+st]); __syncthreads(); }
  const float M = red[0];
  __syncthreads();
  const float e0 = __expf(v0 - M), e1 = __expf(v1 - M);
  red[tid] = e0 + e1;
  __syncthreads();
  for (int st = 128; st; st >>= 1) { if (tid < st) red[tid] += red[tid+st]; __syncthreads(); }
  const float inv = 1.0f / red[0];
  const float a0 = e0*inv, a1 = e1*inv;
  attn[b*512 + tid]       = a0;
  attn[b*512 + 256 + tid] = a1;
  aT[tid*64 + b]       = a0;
  aT[(256+tid)*64 + b] = a1;
}

__global__ void __launch_bounds__(256) attn_pool(const float* __restrict__ outsum,
                                                 const float* __restrict__ aT,
                                                 float* __restrict__ pooled) {
  const int tid = threadIdx.x;
  const int b = tid & 63, jj = tid >> 6;
  const int j = blockIdx.x*4 + jj;
  float acc = 0.0f;
  #pragma unroll 4
  for (int t = 0; t < 512; ++t)
    acc += aT[t*64 + b] * outsum[((size_t)t*512 + j)*64 + b];
  pooled[j*64 + b] = acc;
}

__global__ void __launch_bounds__(128) pred_kern(const float* __restrict__ pooled,
                                                 const float* __restrict__ Wo,
                                                 const float* __restrict__ bo,
                                                 float* __restrict__ out) {
  const int b = blockIdx.x, o = threadIdx.x;
  float acc = bo[o];
  const float* wr = Wo + o*512;
  #pragma unroll 4
  for (int j = 0; j < 512; j += 4) {
    const float4 w = *(const float4*)(wr + j);
    acc += w.x*pooled[(j+0)*64 + b] + w.y*pooled[(j+1)*64 + b]
         + w.z*pooled[(j+2)*64 + b] + w.w*pooled[(j+3)*64 + b];
  }
  out[b*128 + o] = acc;
}

extern "C" void kernel_launch(void* const* d_in, const int* in_sizes, int n_in,
                              void* d_out, int out_size, void* d_ws, size_t ws_size,
                              hipStream_t stream) {
  (void)in_sizes; (void)n_in; (void)out_size; (void)ws_size;
  const float* x    = (const float*)d_in[0];
  const float* Wih0 = (const float*)d_in[1];
  const float* Whh0 = (const float*)d_in[2];
  const float* b0   = (const float*)d_in[3];
  const float* Wih1 = (const float*)d_in[4];
  const float* Whh1 = (const float*)d_in[5];
  const float* b1   = (const float*)d_in[6];
  const float* Wa   = (const float*)d_in[7];
  const float* ba   = (const float*)d_in[8];
  const float* Wo   = (const float*)d_in[9];
  const float* bo   = (const float*)d_in[10];
  float* out = (float*)d_out;
  char* wsb  = (char*)d_ws;

  // zero hbuf + cstore + flags (contiguous)
  hipMemsetAsync(wsb + OFF_HBUF, 0, SZ_HBUF + SZ_CST + SZ_FLG, stream);

  float* xw0[2] = { (float*)(wsb + OFF_OUT), (float*)(wsb + OFF_OUT + SZB0) };
  float* xw1[2] = { (float*)(wsb + OFF_XW1), (float*)(wsb + OFF_XW1 + SZB1) };
  const unsigned short* h0p = (const unsigned short*)(wsb + OFF_H0);

  // layer-0 chunk-0 xw prologue (MFMA split-bf16 path)
  xw_gemm<<<dim3(16, SCH0, 2), 256, 0, stream>>>(x, nullptr, Wih0, b0, xw0[0], 0, SCH0);

  // layer 0: fused recurrence + next-chunk GEMM (last dispatch runs no gemm)
  for (int c = 0; c < NCH0; ++c) {
    const bool last = (c == NCH0 - 1);
    fused_step<<<dim3(2*NWG), dim3(256), FUSED_LDS, stream>>>(
        Whh0, xw0[c & 1], xw0[(c + 1) & 1],
        x, nullptr, Wih0, b0,
        wsb, 0, c*SCH0, SCH0,
        (c + 1)*SCH0, SCH0, last ? 0 : 16*SCH0*2);
  }

  // layer-1 chunk-0 xw (needs ALL of h0 -> standalone, dispatch-ordered)
  xw_gemm<<<dim3(16, SCH1, 2), 256, 0, stream>>>(nullptr, h0p, Wih1, b1, xw1[0], 0, SCH1);

  // outsum becomes live now; zero it (xw0 double buffer no longer needed)
  hipMemsetAsync(wsb + OFF_OUT, 0, SZ_OUT, stream);

  // layer 1
  for (int c = 0; c < NCH1; ++c) {
    const bool last = (c == NCH1 - 1);
    fused_step<<<dim3(2*NWG), dim3(256), FUSED_LDS, stream>>>(
        Whh1, xw1[c & 1], xw1[(c + 1) & 1],
        nullptr, h0p, Wih1, b1,
        wsb, 1, c*SCH1, SCH1,
        (c + 1)*SCH1, SCH1, last ? 0 : 16*SCH1*2);
  }

  attn_logits <<<512, 256, 0, stream>>>((float*)(wsb + OFF_OUT), Wa, ba, (float*)(wsb + OFF_E));
  attn_softmax<<< 64, 256, 0, stream>>>((float*)(wsb + OFF_E), out + 8192, (float*)(wsb + OFF_AT));
  attn_pool   <<<128, 256, 0, stream>>>((float*)(wsb + OFF_OUT), (float*)(wsb + OFF_AT),
                                        (float*)(wsb + OFF_POOL));
  pred_kern   <<< 64, 128, 0, stream>>>((float*)(wsb + OFF_POOL), Wo, bo, out);
}